// Round 1
// baseline (758.024 us; speedup 1.0000x reference)
//
#include <hip/hip_runtime.h>
#include <hip/hip_bf16.h>

#define NN 4096
#define EE 2048
#define RR 4
#define FF 128
#define HDD 256

typedef __attribute__((ext_vector_type(4))) float floatx4;
typedef __attribute__((ext_vector_type(8))) __bf16 bf16x8;

__device__ inline unsigned short f2b(float x) {
  // RNE float -> bf16 bits (no NaN/inf in this workload)
  unsigned int u = __float_as_uint(x);
  unsigned int r = u + 0x7fffu + ((u >> 16) & 1u);
  return (unsigned short)(r >> 16);
}

// ---------------- small prep: softmax(rel_attn), sigmoid(imp) ----------------
__global__ void k_prep(const float* rel, const float* imp, float* rw, float* sig) {
  if (threadIdx.x == 0) {
    float m = -1e30f;
    for (int r = 0; r < RR; r++) m = fmaxf(m, rel[r]);
    float e[RR], s = 0.f;
    for (int r = 0; r < RR; r++) { e[r] = expf(rel[r] - m); s += e[r]; }
    for (int r = 0; r < RR; r++) rw[r] = e[r] / s;
    for (int i = 0; i < 3 * RR; i++) sig[i] = 1.0f / (1.0f + expf(-imp[i]));
  }
}

// ---------------- node degrees: dv[r][n] = rsqrt(rw*rowsum(H)+eps) ----------------
__global__ void k_dv(const float* __restrict__ H, const float* __restrict__ rw, float* __restrict__ dv) {
  int wave = (blockIdx.x << 2) | (threadIdx.x >> 6);
  int lane = threadIdx.x & 63;
  int r = wave >> 12, n = wave & (NN - 1);
  const float* row = H + ((size_t)r * NN + n) * EE;
  float s = 0.f;
  for (int e = lane; e < EE; e += 64) s += row[e];
  for (int off = 32; off; off >>= 1) s += __shfl_down(s, off);
  if (lane == 0) dv[wave] = rsqrtf(rw[r] * s + 1e-8f);
}

// ---------------- edge degrees (partial col sums + finalize) ----------------
__global__ void k_de_part(const float* __restrict__ H, float* __restrict__ de_acc) {
  int e = blockIdx.x * 256 + threadIdx.x;
  int r = blockIdx.y;
  int chunk = blockIdx.z;
  const float* base = H + ((size_t)r * NN + (size_t)chunk * 256) * EE + e;
  float s = 0.f;
  for (int i = 0; i < 256; i++) s += base[(size_t)i * EE];
  atomicAdd(&de_acc[r * EE + e], s);
}
__global__ void k_de_fin(const float* __restrict__ rw, float* __restrict__ de) {
  int i = blockIdx.x * 256 + threadIdx.x;
  int r = i / EE;
  de[i] = rsqrtf(rw[r] * de[i] + 1e-8f);
}

// ------- build theta[r][n][e] (bf16) and thetaT[r][e][n] via LDS transpose -------
__global__ void k_build_theta(const float* __restrict__ H, const float* __restrict__ rw,
                              const float* __restrict__ dv, const float* __restrict__ de,
                              unsigned short* __restrict__ theta, unsigned short* __restrict__ thetaT) {
  __shared__ unsigned short tile[64][65];
  int r = blockIdx.z;
  int e0 = blockIdx.x * 64, n0 = blockIdx.y * 64;
  float rwr = rw[r];
  int tr = threadIdx.x >> 4, tc = threadIdx.x & 15;
  float de0 = de[r * EE + e0 + tc * 4 + 0];
  float de1 = de[r * EE + e0 + tc * 4 + 1];
  float de2 = de[r * EE + e0 + tc * 4 + 2];
  float de3 = de[r * EE + e0 + tc * 4 + 3];
#pragma unroll
  for (int i = 0; i < 4; i++) {
    int n = n0 + tr + 16 * i;
    float d = rwr * dv[r * NN + n];
    float4 h = *(const float4*)(H + ((size_t)r * NN + n) * EE + e0 + tc * 4);
    unsigned short b0 = f2b(h.x * d * de0);
    unsigned short b1 = f2b(h.y * d * de1);
    unsigned short b2 = f2b(h.z * d * de2);
    unsigned short b3 = f2b(h.w * d * de3);
    ushort4 o; o.x = b0; o.y = b1; o.z = b2; o.w = b3;
    *(ushort4*)(theta + ((size_t)r * NN + n) * EE + e0 + tc * 4) = o;
    tile[tr + 16 * i][tc * 4 + 0] = b0;
    tile[tr + 16 * i][tc * 4 + 1] = b1;
    tile[tr + 16 * i][tc * 4 + 2] = b2;
    tile[tr + 16 * i][tc * 4 + 3] = b3;
  }
  __syncthreads();
#pragma unroll
  for (int i = 0; i < 4; i++) {
    int e = e0 + tr + 16 * i;
    ushort4 o;
    o.x = tile[tc * 4 + 0][tr + 16 * i];
    o.y = tile[tc * 4 + 1][tr + 16 * i];
    o.z = tile[tc * 4 + 2][tr + 16 * i];
    o.w = tile[tc * 4 + 3][tr + 16 * i];
    *(ushort4*)(thetaT + ((size_t)r * EE + e) * NN + n0 + tc * 4) = o;
  }
}

// -------- f32 -> bf16 convert, writing row-major and transposed copies --------
__global__ void k_cvt_dual(const float* __restrict__ src, unsigned short* __restrict__ dst,
                           unsigned short* __restrict__ dstT, int M, int C) {
  __shared__ unsigned short tile[64][65];
  int c0 = blockIdx.x * 64, m0 = blockIdx.y * 64;
  int tr = threadIdx.x >> 4, tc = threadIdx.x & 15;
#pragma unroll
  for (int i = 0; i < 4; i++) {
    int m = m0 + tr + 16 * i;
    float4 v = *(const float4*)(src + (size_t)m * C + c0 + tc * 4);
    ushort4 o; o.x = f2b(v.x); o.y = f2b(v.y); o.z = f2b(v.z); o.w = f2b(v.w);
    *(ushort4*)(dst + (size_t)m * C + c0 + tc * 4) = o;
    tile[tr + 16 * i][tc * 4 + 0] = o.x;
    tile[tr + 16 * i][tc * 4 + 1] = o.y;
    tile[tr + 16 * i][tc * 4 + 2] = o.z;
    tile[tr + 16 * i][tc * 4 + 3] = o.w;
  }
  __syncthreads();
#pragma unroll
  for (int i = 0; i < 4; i++) {
    int c = c0 + tr + 16 * i;
    ushort4 o;
    o.x = tile[tc * 4 + 0][tr + 16 * i];
    o.y = tile[tc * 4 + 1][tr + 16 * i];
    o.z = tile[tc * 4 + 2][tr + 16 * i];
    o.w = tile[tc * 4 + 3][tr + 16 * i];
    *(ushort4*)(dstT + (size_t)c * M + m0 + tc * 4) = o;
  }
}

// ---------------- bf16 tile transpose: src[z][M][C] -> dst[z][C][M] ----------------
__global__ void k_tr(const unsigned short* __restrict__ src, unsigned short* __restrict__ dst, int M, int C) {
  __shared__ unsigned short tile[64][65];
  int z = blockIdx.z;
  int c0 = blockIdx.x * 64, m0 = blockIdx.y * 64;
  const unsigned short* s = src + (size_t)z * M * C;
  unsigned short* d = dst + (size_t)z * M * C;
  int tr = threadIdx.x >> 4, tc = threadIdx.x & 15;
#pragma unroll
  for (int i = 0; i < 4; i++) {
    int m = m0 + tr + 16 * i;
    ushort4 v = *(const ushort4*)(s + (size_t)m * C + c0 + tc * 4);
    tile[tr + 16 * i][tc * 4 + 0] = v.x;
    tile[tr + 16 * i][tc * 4 + 1] = v.y;
    tile[tr + 16 * i][tc * 4 + 2] = v.z;
    tile[tr + 16 * i][tc * 4 + 3] = v.w;
  }
  __syncthreads();
#pragma unroll
  for (int i = 0; i < 4; i++) {
    int c = c0 + tr + 16 * i;
    ushort4 v;
    v.x = tile[tc * 4 + 0][tr + 16 * i];
    v.y = tile[tc * 4 + 1][tr + 16 * i];
    v.z = tile[tc * 4 + 2][tr + 16 * i];
    v.w = tile[tc * 4 + 3][tr + 16 * i];
    *(ushort4*)(d + (size_t)c * M + m0 + tc * 4) = v;
  }
}

// -------- WcatT[o][r*Fin+f] = bf16(sig_r * W[r][f][o]) (layers 1,2; Fout=HDD) --------
__global__ void k_wcat(const float* __restrict__ W, const float* __restrict__ sig, int loff, int Fin,
                       unsigned short* __restrict__ WT) {
  int idx = blockIdx.x * 256 + threadIdx.x;
  int o = idx % HDD;
  int f = (idx / HDD) % Fin;
  int r = idx / (HDD * Fin);
  WT[(size_t)o * (RR * Fin) + r * Fin + f] = f2b(sig[loff + r] * W[((size_t)r * Fin + f) * HDD + o]);
}

// -------- W3T[r][o][f] = bf16(sig3_r * W3[r][f][o]) --------
__global__ void k_w3t(const float* __restrict__ W3, const float* __restrict__ sig, unsigned short* __restrict__ WT) {
  int idx = blockIdx.x * 256 + threadIdx.x;
  int o = idx % FF;
  int f = (idx / FF) % HDD;
  int r = idx / (FF * HDD);
  WT[((size_t)r * FF + o) * HDD + f] = f2b(sig[2 * RR + r] * W3[((size_t)r * HDD + f) * FF + o]);
}

// ---------------- the MFMA GEMM: C[M x Ncols] = sum_rr A[M x K] * BT[Ncols x K]^T ----------------
// A row-major (lda), BT holds B transposed: row = output col, k contiguous (ldb).
// mode 0: bf16 store to Cb at c_rs*blockIdx.z flat offset; mode 1: f32 + bias; mode 2: f32 + bias + residual.
__global__ __launch_bounds__(256) void k_gemm(
    const unsigned short* __restrict__ A, const unsigned short* __restrict__ BT,
    int M, int K, int lda, int ldb,
    size_t a_rs, size_t b_rs, int rcount, int mode,
    unsigned short* __restrict__ Cb, float* __restrict__ Cf, size_t c_rs, int ldc,
    const float* __restrict__ bias, const float* __restrict__ res) {
  __shared__ unsigned short Al[64 * 32];
  __shared__ unsigned short Bl[64 * 32];
  int tid = threadIdx.x;
  int m0 = blockIdx.x * 64, n0 = blockIdx.y * 64;
  int rz = blockIdx.z;
  int sm = tid >> 2, sk = (tid & 3) * 8;
  int wid = tid >> 6, lane = tid & 63;
  int wm = (wid >> 1) * 32, wn = (wid & 1) * 32;
  int fm = lane & 15, quad = lane >> 4;
  floatx4 acc[2][2];
  acc[0][0] = 0; acc[0][1] = 0; acc[1][0] = 0; acc[1][1] = 0;
  for (int rr = 0; rr < rcount; rr++) {
    const unsigned short* Ab = A + (size_t)(rz + rr) * a_rs + (size_t)(m0 + sm) * lda;
    const unsigned short* Bb = BT + (size_t)(rz + rr) * b_rs + (size_t)(n0 + sm) * ldb;
    for (int k0 = 0; k0 < K; k0 += 32) {
      *(bf16x8*)&Al[sm * 32 + sk] = *(const bf16x8*)&Ab[k0 + sk];
      *(bf16x8*)&Bl[sm * 32 + sk] = *(const bf16x8*)&Bb[k0 + sk];
      __syncthreads();
      bf16x8 a0 = *(bf16x8*)&Al[(wm + fm) * 32 + quad * 8];
      bf16x8 a1 = *(bf16x8*)&Al[(wm + 16 + fm) * 32 + quad * 8];
      bf16x8 b0 = *(bf16x8*)&Bl[(wn + fm) * 32 + quad * 8];
      bf16x8 b1 = *(bf16x8*)&Bl[(wn + 16 + fm) * 32 + quad * 8];
      acc[0][0] = __builtin_amdgcn_mfma_f32_16x16x32_bf16(a0, b0, acc[0][0], 0, 0, 0);
      acc[0][1] = __builtin_amdgcn_mfma_f32_16x16x32_bf16(a0, b1, acc[0][1], 0, 0, 0);
      acc[1][0] = __builtin_amdgcn_mfma_f32_16x16x32_bf16(a1, b0, acc[1][0], 0, 0, 0);
      acc[1][1] = __builtin_amdgcn_mfma_f32_16x16x32_bf16(a1, b1, acc[1][1], 0, 0, 0);
      __syncthreads();
    }
  }
#pragma unroll
  for (int mi = 0; mi < 2; mi++)
#pragma unroll
    for (int ni = 0; ni < 2; ni++)
#pragma unroll
      for (int v = 0; v < 4; v++) {
        int row = m0 + wm + mi * 16 + quad * 4 + v;
        int col = n0 + wn + ni * 16 + fm;
        float val = acc[mi][ni][v];
        if (mode == 0) {
          Cb[c_rs * rz + (size_t)row * ldc + col] = f2b(val);
        } else {
          val += bias[col];
          if (mode == 2) val += res[(size_t)row * ldc + col];
          Cf[(size_t)row * ldc + col] = val;
        }
      }
}

// ---------------- column stats (sum, sumsq) over N rows of [N x HDD] ----------------
__global__ void k_colstats(const float* __restrict__ x, float* __restrict__ cs, float* __restrict__ cs2) {
  int col = threadIdx.x;
  int row0 = blockIdx.y * 64;
  float s = 0.f, s2 = 0.f;
  for (int i = 0; i < 64; i++) {
    float v = x[(size_t)(row0 + i) * HDD + col];
    s += v; s2 += v * v;
  }
  atomicAdd(&cs[col], s);
  atomicAdd(&cs2[col], s2);
}

// ---------------- BN (batch stats) -> LN -> ELU -> bf16 out [N x HDD] ----------------
__global__ void k_bnlnelu(const float* __restrict__ x, const float* __restrict__ cs, const float* __restrict__ cs2,
                          const float* __restrict__ bg, const float* __restrict__ bb,
                          const float* __restrict__ lg, const float* __restrict__ lb,
                          unsigned short* __restrict__ out) {
  int wid = threadIdx.x >> 6, lane = threadIdx.x & 63;
  int n = blockIdx.x * 4 + wid;
  float y[4];
  float m = 0.f;
#pragma unroll
  for (int j = 0; j < 4; j++) {
    int c = lane + 64 * j;
    float mu = cs[c] * (1.0f / NN);
    float var = cs2[c] * (1.0f / NN) - mu * mu;
    float xv = x[(size_t)n * HDD + c];
    y[j] = (xv - mu) * rsqrtf(var + 1e-5f) * bg[c] + bb[c];
    m += y[j];
  }
  for (int off = 32; off; off >>= 1) m += __shfl_down(m, off);
  m = __shfl(m, 0) * (1.0f / HDD);
  float var = 0.f;
#pragma unroll
  for (int j = 0; j < 4; j++) { float d = y[j] - m; var += d * d; }
  for (int off = 32; off; off >>= 1) var += __shfl_down(var, off);
  var = __shfl(var, 0) * (1.0f / HDD);
  float inv = rsqrtf(var + 1e-5f);
#pragma unroll
  for (int j = 0; j < 4; j++) {
    int c = lane + 64 * j;
    float z = (y[j] - m) * inv * lg[c] + lb[c];
    z = z > 0.f ? z : expm1f(z);
    out[(size_t)n * HDD + c] = f2b(z);
  }
}

extern "C" void kernel_launch(void* const* d_in, const int* in_sizes, int n_in,
                              void* d_out, int out_size, void* d_ws, size_t ws_size,
                              hipStream_t stream) {
  const float* X   = (const float*)d_in[0];
  const float* H   = (const float*)d_in[1];
  const float* W1  = (const float*)d_in[2];
  const float* W2  = (const float*)d_in[3];
  const float* W3  = (const float*)d_in[4];
  const float* imp = (const float*)d_in[5];
  const float* b1  = (const float*)d_in[6];
  const float* b2  = (const float*)d_in[7];
  const float* b3  = (const float*)d_in[8];
  const float* bng = (const float*)d_in[9];
  const float* bnb = (const float*)d_in[10];
  const float* lng = (const float*)d_in[11];
  const float* lnb = (const float*)d_in[12];
  const float* rel = (const float*)d_in[13];

  char* w = (char*)d_ws;
  size_t off = 0;
  auto alloc = [&](size_t bytes) -> void* {
    void* p = w + off;
    off += (bytes + 255) & ~(size_t)255;
    return p;
  };
  float* rw       = (float*)alloc(16);
  float* sig      = (float*)alloc(48);
  float* dv       = (float*)alloc((size_t)RR * NN * 4);
  float* de       = (float*)alloc((size_t)RR * EE * 4);
  float* colsum   = (float*)alloc(HDD * 4);
  float* colsumsq = (float*)alloc(HDD * 4);
  unsigned short* theta  = (unsigned short*)alloc((size_t)RR * NN * EE * 2);
  unsigned short* thetaT = (unsigned short*)alloc((size_t)RR * NN * EE * 2);
  unsigned short* Xb     = (unsigned short*)alloc((size_t)NN * HDD * 2);
  unsigned short* XbT    = (unsigned short*)alloc((size_t)NN * HDD * 2);
  unsigned short* tb     = (unsigned short*)alloc((size_t)RR * EE * HDD * 2);
  unsigned short* tbT    = (unsigned short*)alloc((size_t)RR * EE * HDD * 2);
  unsigned short* Hcat   = (unsigned short*)alloc((size_t)NN * RR * HDD * 2);
  unsigned short* WcatT  = (unsigned short*)alloc((size_t)HDD * RR * HDD * 2);
  unsigned short* Y      = (unsigned short*)alloc((size_t)RR * NN * FF * 2);
  unsigned short* YT     = (unsigned short*)alloc((size_t)RR * NN * FF * 2);
  float* convout         = (float*)alloc((size_t)NN * HDD * 4);
  (void)ws_size; (void)in_sizes; (void)n_in; (void)out_size;

  // --- prep ---
  k_prep<<<1, 64, 0, stream>>>(rel, imp, rw, sig);
  k_dv<<<(RR * NN) / 4, 256, 0, stream>>>(H, rw, dv);
  hipMemsetAsync(de, 0, (size_t)RR * EE * 4, stream);
  k_de_part<<<dim3(EE / 256, RR, NN / 256), 256, 0, stream>>>(H, de);
  k_de_fin<<<(RR * EE) / 256, 256, 0, stream>>>(rw, de);
  k_build_theta<<<dim3(EE / 64, NN / 64, RR), 256, 0, stream>>>(H, rw, dv, de, theta, thetaT);
  k_cvt_dual<<<dim3(FF / 64, NN / 64), 256, 0, stream>>>(X, Xb, XbT, NN, FF);

  // --- layer 1 (F=128 -> HD=256) ---
  k_gemm<<<dim3(EE / 64, FF / 64, RR), 256, 0, stream>>>(thetaT, XbT, EE, NN, NN, NN,
        (size_t)EE * NN, 0, 1, 0, tb, nullptr, (size_t)EE * FF, FF, nullptr, nullptr);
  k_tr<<<dim3(FF / 64, EE / 64, RR), 256, 0, stream>>>(tb, tbT, EE, FF);
  k_gemm<<<dim3(NN / 64, FF / 64, RR), 256, 0, stream>>>(theta, tbT, NN, EE, EE, EE,
        (size_t)NN * EE, (size_t)FF * EE, 1, 0, Hcat, nullptr, (size_t)FF, RR * FF, nullptr, nullptr);
  k_wcat<<<(RR * FF * HDD) / 256, 256, 0, stream>>>(W1, sig, 0, FF, WcatT);
  k_gemm<<<dim3(NN / 64, HDD / 64, 1), 256, 0, stream>>>(Hcat, WcatT, NN, RR * FF, RR * FF, RR * FF,
        0, 0, 1, 1, nullptr, convout, 0, HDD, b1, nullptr);
  hipMemsetAsync(colsum, 0, HDD * 4, stream);
  hipMemsetAsync(colsumsq, 0, HDD * 4, stream);
  k_colstats<<<dim3(1, NN / 64), 256, 0, stream>>>(convout, colsum, colsumsq);
  k_bnlnelu<<<NN / 4, 256, 0, stream>>>(convout, colsum, colsumsq, bng, bnb, lng, lnb, Xb);
  k_tr<<<dim3(HDD / 64, NN / 64, 1), 256, 0, stream>>>(Xb, XbT, NN, HDD);

  // --- layer 2 (HD=256 -> HD=256) ---
  k_gemm<<<dim3(EE / 64, HDD / 64, RR), 256, 0, stream>>>(thetaT, XbT, EE, NN, NN, NN,
        (size_t)EE * NN, 0, 1, 0, tb, nullptr, (size_t)EE * HDD, HDD, nullptr, nullptr);
  k_tr<<<dim3(HDD / 64, EE / 64, RR), 256, 0, stream>>>(tb, tbT, EE, HDD);
  k_gemm<<<dim3(NN / 64, HDD / 64, RR), 256, 0, stream>>>(theta, tbT, NN, EE, EE, EE,
        (size_t)NN * EE, (size_t)HDD * EE, 1, 0, Hcat, nullptr, (size_t)HDD, RR * HDD, nullptr, nullptr);
  k_wcat<<<(RR * HDD * HDD) / 256, 256, 0, stream>>>(W2, sig, RR, HDD, WcatT);
  k_gemm<<<dim3(NN / 64, HDD / 64, 1), 256, 0, stream>>>(Hcat, WcatT, NN, RR * HDD, RR * HDD, RR * HDD,
        0, 0, 1, 1, nullptr, convout, 0, HDD, b2, nullptr);
  hipMemsetAsync(colsum, 0, HDD * 4, stream);
  hipMemsetAsync(colsumsq, 0, HDD * 4, stream);
  k_colstats<<<dim3(1, NN / 64), 256, 0, stream>>>(convout, colsum, colsumsq);
  k_bnlnelu<<<NN / 4, 256, 0, stream>>>(convout, colsum, colsumsq, bng + HDD, bnb + HDD, lng + HDD, lnb + HDD, Xb);
  k_tr<<<dim3(HDD / 64, NN / 64, 1), 256, 0, stream>>>(Xb, XbT, NN, HDD);

  // --- layer 3 (HD=256 -> F=128), W3 applied BEFORE theta products ---
  k_w3t<<<(RR * HDD * FF) / 256, 256, 0, stream>>>(W3, sig, WcatT);  // reuse WcatT as W3T [r][o][f]
  k_gemm<<<dim3(NN / 64, FF / 64, RR), 256, 0, stream>>>(Xb, WcatT, NN, HDD, HDD, HDD,
        0, (size_t)FF * HDD, 1, 0, Y, nullptr, (size_t)NN * FF, FF, nullptr, nullptr);
  k_tr<<<dim3(FF / 64, NN / 64, RR), 256, 0, stream>>>(Y, YT, NN, FF);
  k_gemm<<<dim3(EE / 64, FF / 64, RR), 256, 0, stream>>>(thetaT, YT, EE, NN, NN, NN,
        (size_t)EE * NN, (size_t)FF * NN, 1, 0, tb, nullptr, (size_t)EE * FF, FF, nullptr, nullptr);
  k_tr<<<dim3(FF / 64, EE / 64, RR), 256, 0, stream>>>(tb, tbT, EE, FF);
  k_gemm<<<dim3(NN / 64, FF / 64, 1), 256, 0, stream>>>(theta, tbT, NN, EE, EE, EE,
        (size_t)NN * EE, (size_t)FF * EE, 4, 2, nullptr, (float*)d_out, 0, FF, b3, X);
}